// Round 1
// baseline (38.003 us; speedup 1.0000x reference)
//
#include <hip/hip_runtime.h>

#define D_Z 64
#define D_Y 8
#define NBLK 2048
#define NS 128
#define D_TOTAL (D_Z + NBLK * D_Y)  // 16448
#define N_ZBLK 8                    // z-part split into 8 blocks of 8 rows

// Grid: blocks 0..7 handle the z-part (8 output cols each);
// blocks 8..2055 handle y-block b = blockIdx.x - 8.
// 128 threads per block, one thread per sample s.
__global__ __launch_bounds__(128) void sv_kernel(
    const float* __restrict__ m,
    const float* __restrict__ Lz,     // 2080  = tril(64), row-major tril order
    const float* __restrict__ Ly,     // 73728 = N * 36, per-block tril(8)
    const float* __restrict__ Lyz,    // N*8 x 64 row-major
    const float* __restrict__ eps,    // [128, 16448]
    float* __restrict__ out)          // [128, 16448]
{
    const int bb = blockIdx.x;
    const int s  = threadIdx.x;  // 0..127 (sample)
    const float* epsr = eps + (size_t)s * D_TOTAL;
    float*       outr = out + (size_t)s * D_TOTAL;

    if (bb >= N_ZBLK) {
        // ---------------- y-part: block b, rows r=0..7 ----------------
        const int b = bb - N_ZBLK;
        const float* lyzb = Lyz + (size_t)b * (D_Y * D_Z);  // 8 rows x 64
        const float* mb   = m + D_Z + b * D_Y;

        float acc[8];
        #pragma unroll
        for (int r = 0; r < 8; ++r) acc[r] = mb[r];

        // acc[r] += dot(eps_z[s, 0:64], Lyz[b*8+r, 0:64])
        #pragma unroll
        for (int kk = 0; kk < 16; ++kk) {
            const float4 e = *reinterpret_cast<const float4*>(epsr + 4 * kk);
            #pragma unroll
            for (int r = 0; r < 8; ++r) {
                const float4 l = *reinterpret_cast<const float4*>(lyzb + r * 64 + 4 * kk);
                acc[r] += e.x * l.x + e.y * l.y + e.z * l.z + e.w * l.w;
            }
        }

        // acc[r] += sum_{c<=r} eps[s, 64+b*8+c] * Ly[b][r,c]
        const float4 e0 = *reinterpret_cast<const float4*>(epsr + D_Z + b * D_Y);
        const float4 e1 = *reinterpret_cast<const float4*>(epsr + D_Z + b * D_Y + 4);
        float ey[8] = {e0.x, e0.y, e0.z, e0.w, e1.x, e1.y, e1.z, e1.w};
        const float* lyb = Ly + b * 36;
        #pragma unroll
        for (int r = 0; r < 8; ++r) {
            #pragma unroll
            for (int c = 0; c <= r; ++c) {
                acc[r] += ey[c] * lyb[r * (r + 1) / 2 + c];
            }
        }

        float4 o0 = {acc[0], acc[1], acc[2], acc[3]};
        float4 o1 = {acc[4], acc[5], acc[6], acc[7]};
        *reinterpret_cast<float4*>(outr + D_Z + b * D_Y)     = o0;
        *reinterpret_cast<float4*>(outr + D_Z + b * D_Y + 4) = o1;
    } else {
        // ---------------- z-part: rows j = 8*bb .. 8*bb+7 ----------------
        const int jb = bb * 8;
        float acc[8];
        #pragma unroll
        for (int r = 0; r < 8; ++r) acc[r] = m[jb + r];

        const int kmax = jb + 7;  // largest k needed by any row in this chunk
        for (int k = 0; k <= kmax; ++k) {
            const float e = epsr[k];
            #pragma unroll
            for (int r = 0; r < 8; ++r) {
                const int j = jb + r;
                if (k <= j) {
                    acc[r] += e * Lz[j * (j + 1) / 2 + k];
                }
            }
        }

        float4 o0 = {acc[0], acc[1], acc[2], acc[3]};
        float4 o1 = {acc[4], acc[5], acc[6], acc[7]};
        *reinterpret_cast<float4*>(outr + jb)     = o0;
        *reinterpret_cast<float4*>(outr + jb + 4) = o1;
    }
}

extern "C" void kernel_launch(void* const* d_in, const int* in_sizes, int n_in,
                              void* d_out, int out_size, void* d_ws, size_t ws_size,
                              hipStream_t stream) {
    const float* m   = (const float*)d_in[0];
    const float* Lz  = (const float*)d_in[1];
    const float* Ly  = (const float*)d_in[2];
    const float* Lyz = (const float*)d_in[3];
    const float* eps = (const float*)d_in[4];
    float* out = (float*)d_out;

    dim3 grid(NBLK + N_ZBLK);  // 2056
    dim3 block(128);
    hipLaunchKernelGGL(sv_kernel, grid, block, 0, stream,
                       m, Lz, Ly, Lyz, eps, out);
}

// Round 2
// 25.478 us; speedup vs baseline: 1.4916x; 1.4916x over previous
//
#include <hip/hip_runtime.h>

#define D_Z 64
#define D_Y 8
#define NBLK 2048
#define NS 128
#define D_TOTAL (D_Z + NBLK * D_Y)  // 16448
#define NY (NBLK * D_Y)             // 16384

#define TILE_J 256                  // y-columns per block
#define S_CHUNK 16                  // samples per block
#define N_SCH (NS / S_CHUNK)        // 8
#define N_JT (NY / TILE_J)          // 64
#define N_ZB N_SCH                  // 8 z-part blocks (one per sample chunk)

// Grid: blocks 0..7 -> z-part (cols 0..63, one 16-sample chunk each)
//        blocks 8..519 -> y-part tile (jt = t/8, sc = t%8)
// 256 threads; y-part: thread = one output column j, loops 16 samples.
__global__ __launch_bounds__(256) void sv_kernel(
    const float* __restrict__ m,
    const float* __restrict__ Lz,     // tril(64) row-major tril order
    const float* __restrict__ Ly,     // N * 36 per-block tril(8)
    const float* __restrict__ Lyz,    // [NY x 64] row-major
    const float* __restrict__ eps,    // [128, 16448]
    float* __restrict__ out)          // [128, 16448]
{
    __shared__ float eps_z[S_CHUNK][D_Z];      // 4 KB
    __shared__ float eps_y[S_CHUNK][TILE_J];   // 16 KB

    const int tid = threadIdx.x;
    const int bb  = blockIdx.x;

    if (bb >= N_ZB) {
        // ---------------- y-part ----------------
        const int t  = bb - N_ZB;
        const int jt = t >> 3;      // / N_SCH
        const int sc = t & 7;       // % N_SCH
        const int j0 = jt * TILE_J;
        const int s0 = sc * S_CHUNK;

        // stage eps_z chunk: 16 rows x 64 cols (one float4 per thread)
        {
            const int row = tid >> 4;          // 0..15
            const int c4  = (tid & 15) << 2;   // 0..60
            *reinterpret_cast<float4*>(&eps_z[row][c4]) =
                *reinterpret_cast<const float4*>(&eps[(size_t)(s0 + row) * D_TOTAL + c4]);
        }
        // stage eps_y chunk: 16 rows x 256 cols (4 float4 per thread)
        #pragma unroll
        for (int p = 0; p < 4; ++p) {
            const int row = (tid >> 6) + (p << 2);   // 0..15
            const int c4  = (tid & 63) << 2;         // 0..252
            *reinterpret_cast<float4*>(&eps_y[row][c4]) =
                *reinterpret_cast<const float4*>(
                    &eps[(size_t)(s0 + row) * D_TOTAL + D_Z + j0 + c4]);
        }
        __syncthreads();

        const int jg    = j0 + tid;        // global y-col (0..16383)
        const int r     = tid & 7;         // row within 8-block
        const int bloc  = tid >> 3;        // local 8-group index
        const int bglob = jg >> 3;         // global y-block

        // Lyz row j in registers (64 floats)
        float4 lz[16];
        const float4* lyzr = reinterpret_cast<const float4*>(Lyz + (size_t)jg * D_Z);
        #pragma unroll
        for (int k = 0; k < 16; ++k) lz[k] = lyzr[k];

        // Ly triangle row, zero-padded to 8 (avoids divergence)
        float lyr[8];
        const float* lyb = Ly + bglob * 36 + r * (r + 1) / 2;
        #pragma unroll
        for (int c = 0; c < 8; ++c) lyr[c] = (c <= r) ? lyb[c] : 0.0f;

        const float mj = m[D_Z + jg];

        for (int si = 0; si < S_CHUNK; ++si) {
            float acc = mj;
            #pragma unroll
            for (int k = 0; k < 16; ++k) {
                const float4 e = *reinterpret_cast<const float4*>(&eps_z[si][k << 2]);
                acc += e.x * lz[k].x + e.y * lz[k].y + e.z * lz[k].z + e.w * lz[k].w;
            }
            const float4 ey0 = *reinterpret_cast<const float4*>(&eps_y[si][bloc << 3]);
            const float4 ey1 = *reinterpret_cast<const float4*>(&eps_y[si][(bloc << 3) + 4]);
            acc += ey0.x * lyr[0] + ey0.y * lyr[1] + ey0.z * lyr[2] + ey0.w * lyr[3];
            acc += ey1.x * lyr[4] + ey1.y * lyr[5] + ey1.z * lyr[6] + ey1.w * lyr[7];
            out[(size_t)(s0 + si) * D_TOTAL + D_Z + jg] = acc;
        }
    } else {
        // ---------------- z-part: cols 0..63, sample chunk bb ----------------
        const int s0 = bb * S_CHUNK;
        {
            const int row = tid >> 4;
            const int c4  = (tid & 15) << 2;
            *reinterpret_cast<float4*>(&eps_z[row][c4]) =
                *reinterpret_cast<const float4*>(&eps[(size_t)(s0 + row) * D_TOTAL + c4]);
        }
        __syncthreads();

        const int j  = tid & 63;
        const int sg = tid >> 6;        // 0..3, wave-uniform
        const float mj = m[j];
        const float* lzr = Lz + j * (j + 1) / 2;

        #pragma unroll
        for (int ss = 0; ss < 4; ++ss) {
            const int si = (sg << 2) + ss;
            float acc = mj;
            for (int k = 0; k <= j; ++k) acc += eps_z[si][k] * lzr[k];
            out[(size_t)(s0 + si) * D_TOTAL + j] = acc;
        }
    }
}

extern "C" void kernel_launch(void* const* d_in, const int* in_sizes, int n_in,
                              void* d_out, int out_size, void* d_ws, size_t ws_size,
                              hipStream_t stream) {
    const float* m   = (const float*)d_in[0];
    const float* Lz  = (const float*)d_in[1];
    const float* Ly  = (const float*)d_in[2];
    const float* Lyz = (const float*)d_in[3];
    const float* eps = (const float*)d_in[4];
    float* out = (float*)d_out;

    dim3 grid(N_ZB + N_JT * N_SCH);  // 520
    dim3 block(256);
    hipLaunchKernelGGL(sv_kernel, grid, block, 0, stream,
                       m, Lz, Ly, Lyz, eps, out);
}

// Round 3
// 19.510 us; speedup vs baseline: 1.9479x; 1.3059x over previous
//
#include <hip/hip_runtime.h>

#define D_Z 64
#define D_Y 8
#define NBLK 2048
#define NS 128
#define D_TOTAL 16448
#define NY 16384

#define TJ 32                 // y-cols per block
#define N_YB (NY / TJ)        // 512
#define N_ZB 8                // z-part blocks

typedef __attribute__((ext_vector_type(8))) short bf16x8;
typedef __attribute__((ext_vector_type(4))) float f32x4;

// fp32 -> bf16 round-to-nearest-even
__device__ inline short f2bf(float x) {
    union { float f; unsigned u; } v; v.f = x;
    return (short)((v.u + 0x7fffu + ((v.u >> 16) & 1u)) >> 16);
}

__device__ inline bf16x8 pack_bf16x8(float4 a, float4 b) {
    bf16x8 r = { f2bf(a.x), f2bf(a.y), f2bf(a.z), f2bf(a.w),
                 f2bf(b.x), f2bf(b.y), f2bf(b.z), f2bf(b.w) };
    return r;
}

// Grid: blocks 0..7 -> z-part (cols 0..63, one 16-sample chunk each).
//       blocks 8..519 -> y-part: 32 y-cols x all 128 samples, MFMA.
__global__ __launch_bounds__(256) void sv_kernel(
    const float* __restrict__ m,
    const float* __restrict__ Lz,     // tril(64), row-major tril order
    const float* __restrict__ Ly,     // N * 36, per-block tril(8)
    const float* __restrict__ Lyz,    // [NY x 64] row-major
    const float* __restrict__ eps,    // [128, 16448]
    float* __restrict__ out)          // [128, 16448]
{
    __shared__ float eps_z[16][D_Z];  // z-part staging only (4 KB)

    const int tid = threadIdx.x;
    const int bb  = blockIdx.x;

    if (bb >= N_ZB) {
        // ======== y-part: GEMM via MFMA + triangular correction ========
        const int t    = bb - N_ZB;
        const int j0   = t * TJ;            // base y-col
        const int w    = tid >> 6;          // wave 0..3
        const int lane = tid & 63;
        const int nt   = w & 1;             // n-tile within block (2 x 16 cols)
        const int mtb  = (w >> 1) * 4;      // first of 4 m-tiles (16 samples each)
        const int ln15 = lane & 15;
        const int lg   = lane >> 4;         // 0..3 (K-chunk / row-group)

        // ---- B fragments: Lyz row jy, fp32 -> bf16 in-register ----
        const int jy = j0 + nt * 16 + ln15;          // y-col 0..16383
        const float* lyzrow = Lyz + (size_t)jy * D_Z;
        bf16x8 bfr[2];
        #pragma unroll
        for (int ks = 0; ks < 2; ++ks) {
            const float4 p0 = *reinterpret_cast<const float4*>(lyzrow + ks * 32 + lg * 8);
            const float4 p1 = *reinterpret_cast<const float4*>(lyzrow + ks * 32 + lg * 8 + 4);
            bfr[ks] = pack_bf16x8(p0, p1);
        }

        // ---- A fragments (eps_z rows) + MFMA ----
        f32x4 acc[4];
        #pragma unroll
        for (int i = 0; i < 4; ++i) acc[i] = (f32x4){0.f, 0.f, 0.f, 0.f};

        #pragma unroll
        for (int i = 0; i < 4; ++i) {
            const int srow = (mtb + i) * 16 + ln15;          // sample row
            const float* er = eps + (size_t)srow * D_TOTAL;  // eps_z part
            #pragma unroll
            for (int ks = 0; ks < 2; ++ks) {
                const float4 a0 = *reinterpret_cast<const float4*>(er + ks * 32 + lg * 8);
                const float4 a1 = *reinterpret_cast<const float4*>(er + ks * 32 + lg * 8 + 4);
                const bf16x8 av = pack_bf16x8(a0, a1);
                acc[i] = __builtin_amdgcn_mfma_f32_16x16x32_bf16(av, bfr[ks], acc[i], 0, 0, 0);
            }
        }

        // ---- epilogue: m[j] + triangular Ly correction, store ----
        const int jg = D_Z + jy;                 // global out col
        const float mj = m[jg];
        const int r = jy & 7;
        const float* lyp = Ly + (jy >> 3) * 36 + r * (r + 1) / 2;  // stays in-block
        float lyr[8];
        #pragma unroll
        for (int c = 0; c < 8; ++c) lyr[c] = (c <= r) ? lyp[c] : 0.0f;

        const size_t eyoff = (size_t)(jg & ~7);  // 8-block base of this col
        #pragma unroll
        for (int i = 0; i < 4; ++i) {
            #pragma unroll
            for (int reg = 0; reg < 4; ++reg) {
                const int s = (mtb + i) * 16 + lg * 4 + reg;   // D row = lg*4+reg
                const float* ey = eps + (size_t)s * D_TOTAL + eyoff;
                const float4 e0 = *reinterpret_cast<const float4*>(ey);
                const float4 e1 = *reinterpret_cast<const float4*>(ey + 4);
                const float corr =
                    e0.x * lyr[0] + e0.y * lyr[1] + e0.z * lyr[2] + e0.w * lyr[3] +
                    e1.x * lyr[4] + e1.y * lyr[5] + e1.z * lyr[6] + e1.w * lyr[7];
                out[(size_t)s * D_TOTAL + jg] = acc[i][reg] + mj + corr;
            }
        }
    } else {
        // ======== z-part: cols 0..63, sample chunk bb (proven in R2) ========
        const int s0 = bb * 16;
        {
            const int row = tid >> 4;
            const int c4  = (tid & 15) << 2;
            *reinterpret_cast<float4*>(&eps_z[row][c4]) =
                *reinterpret_cast<const float4*>(&eps[(size_t)(s0 + row) * D_TOTAL + c4]);
        }
        __syncthreads();

        const int j  = tid & 63;
        const int sg = tid >> 6;
        const float mj = m[j];
        const float* lzr = Lz + j * (j + 1) / 2;

        #pragma unroll
        for (int ss = 0; ss < 4; ++ss) {
            const int si = (sg << 2) + ss;
            float acc = mj;
            for (int k = 0; k <= j; ++k) acc += eps_z[si][k] * lzr[k];
            out[(size_t)(s0 + si) * D_TOTAL + j] = acc;
        }
    }
}

extern "C" void kernel_launch(void* const* d_in, const int* in_sizes, int n_in,
                              void* d_out, int out_size, void* d_ws, size_t ws_size,
                              hipStream_t stream) {
    const float* m   = (const float*)d_in[0];
    const float* Lz  = (const float*)d_in[1];
    const float* Ly  = (const float*)d_in[2];
    const float* Lyz = (const float*)d_in[3];
    const float* eps = (const float*)d_in[4];
    float* out = (float*)d_out;

    dim3 grid(N_ZB + N_YB);  // 520
    dim3 block(256);
    hipLaunchKernelGGL(sv_kernel, grid, block, 0, stream,
                       m, Lz, Ly, Lyz, eps, out);
}